// Round 1
// baseline (152.696 us; speedup 1.0000x reference)
//
#include <hip/hip_runtime.h>

// out[i, p, a, b] = sum_{m,n} A[i, m, a] * B[i, n, b] * C[m, n, p]
// A: (600000, 3, 3), B: (600000, 5, 5), C: (3, 5, 5), out: (600000, 5, 15)
// flat out index: i*75 + p*15 + a*5 + b

#define N_ATOMS 600000
#define TOT (N_ATOMS * 75)

__global__ __launch_bounds__(256) void tb_kernel(const float* __restrict__ A,
                                                 const float* __restrict__ B,
                                                 const float* __restrict__ C,
                                                 float* __restrict__ out) {
    __shared__ float sC[75];  // C[m][n][p] = sC[m*25 + n*5 + p]
    if (threadIdx.x < 75) sC[threadIdx.x] = C[threadIdx.x];
    __syncthreads();

    const int stride = gridDim.x * blockDim.x;
    for (int t = blockIdx.x * blockDim.x + threadIdx.x; t < TOT; t += stride) {
        const int i  = t / 75;
        const int e  = t - i * 75;
        const int p  = e / 15;
        const int ab = e - p * 15;
        const int a  = ab / 5;
        const int b  = ab - a * 5;

        const float* Ai = A + i * 9;
        const float* Bi = B + i * 25;

        // Load the 5 B values reused across m
        float bv0 = Bi[0 * 5 + b];
        float bv1 = Bi[1 * 5 + b];
        float bv2 = Bi[2 * 5 + b];
        float bv3 = Bi[3 * 5 + b];
        float bv4 = Bi[4 * 5 + b];

        float acc = 0.0f;
        #pragma unroll
        for (int m = 0; m < 3; ++m) {
            const float av = Ai[m * 3 + a];
            const float* Cm = &sC[m * 25 + p];  // C[m][n][p] at Cm[n*5]
            acc = fmaf(av * bv0, Cm[0 * 5], acc);
            acc = fmaf(av * bv1, Cm[1 * 5], acc);
            acc = fmaf(av * bv2, Cm[2 * 5], acc);
            acc = fmaf(av * bv3, Cm[3 * 5], acc);
            acc = fmaf(av * bv4, Cm[4 * 5], acc);
        }
        out[t] = acc;
    }
}

extern "C" void kernel_launch(void* const* d_in, const int* in_sizes, int n_in,
                              void* d_out, int out_size, void* d_ws, size_t ws_size,
                              hipStream_t stream) {
    const float* A = (const float*)d_in[0];
    const float* B = (const float*)d_in[1];
    const float* C = (const float*)d_in[2];
    float* out = (float*)d_out;

    const int block = 256;
    const int grid = 2048;  // 256 CUs x 8 blocks/CU; grid-stride covers 45M elements
    tb_kernel<<<grid, block, 0, stream>>>(A, B, C, out);
}

// Round 2
// 58.047 us; speedup vs baseline: 2.6306x; 2.6306x over previous
//
#include <hip/hip_runtime.h>

// out[i, p, a, b] = sum_{m,n} A[i, m, a] * B[i, n, b] * C[m, n, p]
// A: (600000, 3, 3), B: (600000, 5, 5), C: (3, 5, 5), out: (600000, 5, 15)
//
// Tile design: block = 320 threads = 64 atoms x 5 p-values.
//  - stage A-tile (576 fl) + B-tile (1600 fl) to LDS via coalesced float4
//  - thread (i_loc, p): C[:,:,p] in 15 regs (loaded once), reads A row (9) +
//    B row (25) from LDS, computes T[m,b]=sum_n B*C (75 FMA) then
//    out[a,b]=sum_m A*T (45 FMA), writes 15 floats to LDS out-tile
//  - coalesced float4 flush of the 4800-float out-tile

#define N_ATOMS 600000
#define NTILES (N_ATOMS / 64)   // 9375 exact
#define A_FL 576                // 64*9
#define AB_FL 2176              // 576 + 1600
#define O_FL 4800               // 64*75

__global__ __launch_bounds__(320) void tb_kernel(const float* __restrict__ A,
                                                 const float* __restrict__ B,
                                                 const float* __restrict__ C,
                                                 float* __restrict__ out) {
    __shared__ float sAB[AB_FL];
    __shared__ float sO[O_FL];

    const int tid   = threadIdx.x;
    const int i_loc = tid / 5;        // 0..63  (local atom)
    const int p     = tid - i_loc * 5; // 0..4

    // C[m][n][p] into registers (uniform per thread across all tiles)
    float cr[3][5];
    #pragma unroll
    for (int m = 0; m < 3; ++m)
        #pragma unroll
        for (int n = 0; n < 5; ++n)
            cr[m][n] = C[m * 25 + n * 5 + p];

    // ---- staging: 544 float4 = A-tile (144) then B-tile (400), coalesced ----
    auto stage = [&](int tile) {
        const int i0 = tile * 64;
        #pragma unroll
        for (int jj = 0; jj < 2; ++jj) {
            int j = tid + jj * 320;
            if (j < 544) {
                int f0 = j * 4;
                float4 v;
                if (f0 < A_FL) {
                    v = *reinterpret_cast<const float4*>(A + (size_t)i0 * 9 + f0);
                } else {
                    v = *reinterpret_cast<const float4*>(B + (size_t)i0 * 25 + (f0 - A_FL));
                }
                *reinterpret_cast<float4*>(&sAB[f0]) = v;
            }
        }
    };

    int tile = blockIdx.x;
    if (tile >= NTILES) return;

    stage(tile);
    __syncthreads();

    for (; tile < NTILES; tile += gridDim.x) {
        // ---- compute: reads sAB, writes sO ----
        float av[9];
        #pragma unroll
        for (int k = 0; k < 9; ++k) av[k] = sAB[i_loc * 9 + k];
        float bv[25];
        #pragma unroll
        for (int k = 0; k < 25; ++k) bv[k] = sAB[A_FL + i_loc * 25 + k];

        // T[m][b] = sum_n bv[n][b] * cr[m][n]
        float T[3][5];
        #pragma unroll
        for (int m = 0; m < 3; ++m) {
            #pragma unroll
            for (int b = 0; b < 5; ++b) {
                float t = 0.0f;
                #pragma unroll
                for (int n = 0; n < 5; ++n)
                    t = fmaf(bv[n * 5 + b], cr[m][n], t);
                T[m][b] = t;
            }
        }
        // out[a][b] = sum_m av[m][a] * T[m][b]
        #pragma unroll
        for (int a = 0; a < 3; ++a) {
            #pragma unroll
            for (int b = 0; b < 5; ++b) {
                float acc = 0.0f;
                #pragma unroll
                for (int m = 0; m < 3; ++m)
                    acc = fmaf(av[m * 3 + a], T[m][b], acc);
                sO[tid * 15 + a * 5 + b] = acc;
            }
        }

        __syncthreads();

        // prefetch next tile's A/B into sAB (overlaps with flush stores)
        int next = tile + gridDim.x;
        if (next < NTILES) stage(next);

        // ---- flush: 1200 float4, fully coalesced ----
        float* obase = out + (size_t)tile * O_FL;
        #pragma unroll
        for (int jj = 0; jj < 4; ++jj) {
            int j = tid + jj * 320;
            if (j < 1200) {
                float4 v = *reinterpret_cast<const float4*>(&sO[4 * j]);
                *reinterpret_cast<float4*>(obase + 4 * j) = v;
            }
        }

        __syncthreads();
    }
}

extern "C" void kernel_launch(void* const* d_in, const int* in_sizes, int n_in,
                              void* d_out, int out_size, void* d_ws, size_t ws_size,
                              hipStream_t stream) {
    const float* A = (const float*)d_in[0];
    const float* B = (const float*)d_in[1];
    const float* C = (const float*)d_in[2];
    float* out = (float*)d_out;

    const int block = 320;   // 5 waves: 64 atoms x 5 p
    const int grid  = 1280;  // grid-stride over 9375 tiles
    tb_kernel<<<grid, block, 0, stream>>>(A, B, C, out);
}

// Round 3
// 47.007 us; speedup vs baseline: 3.2484x; 1.2349x over previous
//
#include <hip/hip_runtime.h>

// out[i, p, a, b] = sum_{m,n} A[i, m, a] * B[i, n, b] * C[m, n, p]
// A: (600000, 3, 3), B: (600000, 5, 5), C: (3, 5, 5), out: (600000, 5, 15)
//
// Block = 320 threads = 64 atoms x 5 p-values, tile = 64 atoms.
// Pipeline (double-buffered sAB, T14 async-stage split):
//   top of iter : issue next tile's global loads into regs (latency hides
//                 under compute)
//   compute     : read A/B rows from sAB[cur], 120 FMA, write 15 outs to sO
//   barrier
//   stage-write : ds_write staged regs -> sAB[cur^1]   (overlaps flush)
//   flush       : sO -> global, coalesced float4
//   barrier, cur ^= 1

#define N_ATOMS 600000
#define NTILES (N_ATOMS / 64)   // 9375 exact
#define A_FL 576                // 64*9
#define AB_FL 2176              // 576 + 1600
#define O_FL 4800               // 64*75
#define GRID 2048

__global__ __launch_bounds__(320) void tb_kernel(const float* __restrict__ A,
                                                 const float* __restrict__ B,
                                                 const float* __restrict__ C,
                                                 float* __restrict__ out) {
    __shared__ float sAB[2][AB_FL];
    __shared__ float sO[O_FL];

    const int tid   = threadIdx.x;
    const int i_loc = tid / 5;         // 0..63
    const int p     = tid - i_loc * 5; // 0..4

    // C[:, :, p] in 15 registers (uniform across tiles)
    float cr[3][5];
    #pragma unroll
    for (int m = 0; m < 3; ++m)
        #pragma unroll
        for (int n = 0; n < 5; ++n)
            cr[m][n] = C[m * 25 + n * 5 + p];

    // ---- prologue: stage tile0 into buffer 0 ----
    int tile = blockIdx.x;
    {
        const int i0 = tile * 64;
        #pragma unroll
        for (int jj = 0; jj < 2; ++jj) {
            int j = tid + jj * 320;
            if (j < 544) {
                int f0 = j * 4;
                float4 v = (f0 < A_FL)
                    ? *reinterpret_cast<const float4*>(A + (size_t)i0 * 9 + f0)
                    : *reinterpret_cast<const float4*>(B + (size_t)i0 * 25 + (f0 - A_FL));
                *reinterpret_cast<float4*>(&sAB[0][f0]) = v;
            }
        }
    }
    __syncthreads();

    int cur = 0;
    const bool g1v = (tid + 320) < 544;  // second stage slot valid for tid<224
    for (; tile < NTILES; tile += GRID) {
        const int  next      = tile + GRID;
        const bool have_next = next < NTILES;

        // ---- issue next tile's loads into registers (no LDS touch yet) ----
        float4 g0, g1;
        if (have_next) {
            const int i0 = next * 64;
            const int f0 = tid * 4;                  // 0..1276
            g0 = (f0 < A_FL)
                ? *reinterpret_cast<const float4*>(A + (size_t)i0 * 9 + f0)
                : *reinterpret_cast<const float4*>(B + (size_t)i0 * 25 + (f0 - A_FL));
            if (g1v) {
                const int f1 = (tid + 320) * 4;      // 1280..2172, always B side
                g1 = *reinterpret_cast<const float4*>(B + (size_t)i0 * 25 + (f1 - A_FL));
            }
        }

        // ---- compute from sAB[cur] ----
        const float* sab = sAB[cur];
        float av[9];
        #pragma unroll
        for (int k = 0; k < 9; ++k) av[k] = sab[i_loc * 9 + k];
        float bv[25];
        #pragma unroll
        for (int k = 0; k < 25; ++k) bv[k] = sab[A_FL + i_loc * 25 + k];

        // T[m][b] = sum_n bv[n][b] * cr[m][n]
        float T[3][5];
        #pragma unroll
        for (int m = 0; m < 3; ++m) {
            #pragma unroll
            for (int b = 0; b < 5; ++b) {
                float t = 0.0f;
                #pragma unroll
                for (int n = 0; n < 5; ++n)
                    t = fmaf(bv[n * 5 + b], cr[m][n], t);
                T[m][b] = t;
            }
        }
        // out[a][b] = sum_m av[m][a] * T[m][b]
        #pragma unroll
        for (int a = 0; a < 3; ++a) {
            #pragma unroll
            for (int b = 0; b < 5; ++b) {
                float acc = 0.0f;
                #pragma unroll
                for (int m = 0; m < 3; ++m)
                    acc = fmaf(av[m * 3 + a], T[m][b], acc);
                sO[tid * 15 + a * 5 + b] = acc;
            }
        }

        __syncthreads();

        // ---- stage-write regs -> other buffer (overlaps flush) ----
        if (have_next) {
            float* dst = sAB[cur ^ 1];
            *reinterpret_cast<float4*>(&dst[tid * 4]) = g0;
            if (g1v)
                *reinterpret_cast<float4*>(&dst[(tid + 320) * 4]) = g1;
        }

        // ---- flush sO -> global, coalesced ----
        float* obase = out + (size_t)tile * O_FL;
        #pragma unroll
        for (int jj = 0; jj < 4; ++jj) {
            int j = tid + jj * 320;
            if (j < 1200) {
                float4 v = *reinterpret_cast<const float4*>(&sO[4 * j]);
                *reinterpret_cast<float4*>(obase + 4 * j) = v;
            }
        }

        __syncthreads();
        cur ^= 1;
    }
}

extern "C" void kernel_launch(void* const* d_in, const int* in_sizes, int n_in,
                              void* d_out, int out_size, void* d_ws, size_t ws_size,
                              hipStream_t stream) {
    const float* A = (const float*)d_in[0];
    const float* B = (const float*)d_in[1];
    const float* C = (const float*)d_in[2];
    float* out = (float*)d_out;

    tb_kernel<<<GRID, 320, 0, stream>>>(A, B, C, out);
}

// Round 4
// 45.883 us; speedup vs baseline: 3.3280x; 1.0245x over previous
//
#include <hip/hip_runtime.h>

// out[i, p, a, b] = sum_{m,n} A[i, m, a] * B[i, n, b] * C[m, n, p]
// A: (600000, 3, 3), B: (600000, 5, 5), C: (3, 5, 5), out: (600000, 5, 15)
//
// Block = 320 threads = 64 atoms x 5 p-values, tile = 64 atoms.
// Pipeline (double-buffered sAB, raw barriers, counted vmcnt):
//   top    : issue next tile's global loads into regs
//   compute: read A/B rows from sAB[cur], 120 FMA, 15 outs -> sO
//   BAR(lgkm only)                      <- no store drain
//   flush  : sO -> global, coalesced float4 (fire and forget)
//   stage  : ds_write staged regs -> sAB[cur^1]  (vmcnt(4): waits only the
//            g-loads, counted past the 4 newer flush stores)
//   BAR(lgkm only)
// Global stores are never vmcnt(0)-drained inside the loop; they retire in
// the background at HBM pace (T4 counted-wait pattern).

#define N_ATOMS 600000
#define NTILES (N_ATOMS / 64)   // 9375 exact
#define A_FL 576                // 64*9
#define AB_FL 2176              // 576 + 1600
#define O_FL 4800               // 64*75
#define GRID 2048

__device__ __forceinline__ void bar_lgkm() {
    asm volatile("s_waitcnt lgkmcnt(0)" ::: "memory");
    __builtin_amdgcn_s_barrier();
    asm volatile("" ::: "memory");
}

__global__ __launch_bounds__(320) void tb_kernel(const float* __restrict__ A,
                                                 const float* __restrict__ B,
                                                 const float* __restrict__ C,
                                                 float* __restrict__ out) {
    __shared__ float sAB[2][AB_FL];
    __shared__ float sO[O_FL];

    const int tid   = threadIdx.x;
    const int i_loc = tid / 5;         // 0..63
    const int p     = tid - i_loc * 5; // 0..4

    // C[:, :, p] in 15 registers (uniform across tiles)
    float cr[3][5];
    #pragma unroll
    for (int m = 0; m < 3; ++m)
        #pragma unroll
        for (int n = 0; n < 5; ++n)
            cr[m][n] = C[m * 25 + n * 5 + p];

    // ---- prologue: stage tile0 into buffer 0 ----
    int tile = blockIdx.x;
    {
        const int i0 = tile * 64;
        #pragma unroll
        for (int jj = 0; jj < 2; ++jj) {
            int j = tid + jj * 320;
            if (j < 544) {
                int f0 = j * 4;
                float4 v = (f0 < A_FL)
                    ? *reinterpret_cast<const float4*>(A + (size_t)i0 * 9 + f0)
                    : *reinterpret_cast<const float4*>(B + (size_t)i0 * 25 + (f0 - A_FL));
                *reinterpret_cast<float4*>(&sAB[0][f0]) = v;
            }
        }
    }
    bar_lgkm();

    int cur = 0;
    const bool g1v = (tid + 320) < 544;  // second stage slot valid for tid<224
    for (; tile < NTILES; tile += GRID) {
        const int  next      = tile + GRID;
        const bool have_next = next < NTILES;

        // ---- issue next tile's loads into registers ----
        float4 g0, g1;
        if (have_next) {
            const int i0 = next * 64;
            const int f0 = tid * 4;                  // 0..1276
            g0 = (f0 < A_FL)
                ? *reinterpret_cast<const float4*>(A + (size_t)i0 * 9 + f0)
                : *reinterpret_cast<const float4*>(B + (size_t)i0 * 25 + (f0 - A_FL));
            if (g1v) {
                const int f1 = (tid + 320) * 4;      // 1280..2172, always B side
                g1 = *reinterpret_cast<const float4*>(B + (size_t)i0 * 25 + (f1 - A_FL));
            }
        }

        // ---- compute from sAB[cur] ----
        const float* sab = sAB[cur];
        float av[9];
        #pragma unroll
        for (int k = 0; k < 9; ++k) av[k] = sab[i_loc * 9 + k];
        float bv[25];
        #pragma unroll
        for (int k = 0; k < 25; ++k) bv[k] = sab[A_FL + i_loc * 25 + k];

        // T[m][b] = sum_n bv[n][b] * cr[m][n]
        float T[3][5];
        #pragma unroll
        for (int m = 0; m < 3; ++m) {
            #pragma unroll
            for (int b = 0; b < 5; ++b) {
                float t = 0.0f;
                #pragma unroll
                for (int n = 0; n < 5; ++n)
                    t = fmaf(bv[n * 5 + b], cr[m][n], t);
                T[m][b] = t;
            }
        }
        // out[a][b] = sum_m av[m][a] * T[m][b]
        #pragma unroll
        for (int a = 0; a < 3; ++a) {
            #pragma unroll
            for (int b = 0; b < 5; ++b) {
                float acc = 0.0f;
                #pragma unroll
                for (int m = 0; m < 3; ++m)
                    acc = fmaf(av[m * 3 + a], T[m][b], acc);
                sO[tid * 15 + a * 5 + b] = acc;
            }
        }

        bar_lgkm();   // sO writes visible; NO store drain

        // ---- flush sO -> global, coalesced (issued BEFORE stage-write) ----
        float* obase = out + (size_t)tile * O_FL;
        #pragma unroll
        for (int jj = 0; jj < 4; ++jj) {
            int j = tid + jj * 320;
            if (j < 1200) {
                float4 v = *reinterpret_cast<const float4*>(&sO[4 * j]);
                *reinterpret_cast<float4*>(obase + 4 * j) = v;
            }
        }

        // keep flush stores ordered before the g-dependent ds_writes so the
        // implicit wait is a counted vmcnt(4), not a store drain
        asm volatile("" ::: "memory");

        // ---- stage-write regs -> other buffer ----
        if (have_next) {
            float* dst = sAB[cur ^ 1];
            *reinterpret_cast<float4*>(&dst[tid * 4]) = g0;
            if (g1v)
                *reinterpret_cast<float4*>(&dst[(tid + 320) * 4]) = g1;
        }

        bar_lgkm();   // stage writes + flush ds_reads complete; stores fly on
        cur ^= 1;
    }
}

extern "C" void kernel_launch(void* const* d_in, const int* in_sizes, int n_in,
                              void* d_out, int out_size, void* d_ws, size_t ws_size,
                              hipStream_t stream) {
    const float* A = (const float*)d_in[0];
    const float* B = (const float*)d_in[1];
    const float* C = (const float*)d_in[2];
    float* out = (float*)d_out;

    tb_kernel<<<GRID, 320, 0, stream>>>(A, B, C, out);
}

// Round 6
// 44.742 us; speedup vs baseline: 3.4128x; 1.0255x over previous
//
#include <hip/hip_runtime.h>

// out[i, p, a, b] = sum_{m,n} A[i, m, a] * B[i, n, b] * C[m, n, p]
// A: (600000, 3, 3), B: (600000, 5, 5), C: (3, 5, 5), out: (600000, 5, 15)
//
// Block = 320 threads = 64 atoms x 5 p-values, tile = 64 atoms.
// SINGLE-buffered sAB (reg-hop makes dbuf redundant) -> 27.9 KB LDS
// -> 5 blocks/CU (25 waves/CU), up from 4.
// Pipeline per tile (raw lgkm-only barriers, counted vmcnt):
//   top    : issue next tile's global loads into regs
//   compute: read A/B rows from sAB, 120 FMA, 15 outs -> sO
//   BAR(lgkm)                        <- all sAB reads + sO writes done
//   flush  : sO -> global, nontemporal float4 (fire and forget)
//   stage  : ds_write staged regs -> sAB (wait = vmcnt(4), counted past
//            the 4 newer flush stores; prior-tile stores had a full tile
//            of slack)
//   BAR(lgkm)

#define N_ATOMS 600000
#define NTILES (N_ATOMS / 64)   // 9375 exact
#define A_FL 576                // 64*9
#define AB_FL 2176              // 576 + 1600
#define O_FL 4800               // 64*75
#define GRID 2048

typedef float f32x4 __attribute__((ext_vector_type(4)));

__device__ __forceinline__ void bar_lgkm() {
    asm volatile("s_waitcnt lgkmcnt(0)" ::: "memory");
    __builtin_amdgcn_s_barrier();
    asm volatile("" ::: "memory");
}

__global__ __launch_bounds__(320) void tb_kernel(const float* __restrict__ A,
                                                 const float* __restrict__ B,
                                                 const float* __restrict__ C,
                                                 float* __restrict__ out) {
    __shared__ float sAB[AB_FL];
    __shared__ float sO[O_FL];

    const int tid   = threadIdx.x;
    const int i_loc = tid / 5;         // 0..63
    const int p     = tid - i_loc * 5; // 0..4

    // C[:, :, p] in 15 registers (uniform across tiles)
    float cr[3][5];
    #pragma unroll
    for (int m = 0; m < 3; ++m)
        #pragma unroll
        for (int n = 0; n < 5; ++n)
            cr[m][n] = C[m * 25 + n * 5 + p];

    // ---- prologue: stage tile0 ----
    int tile = blockIdx.x;
    {
        const int i0 = tile * 64;
        #pragma unroll
        for (int jj = 0; jj < 2; ++jj) {
            int j = tid + jj * 320;
            if (j < 544) {
                int f0 = j * 4;
                f32x4 v = (f0 < A_FL)
                    ? *reinterpret_cast<const f32x4*>(A + (size_t)i0 * 9 + f0)
                    : *reinterpret_cast<const f32x4*>(B + (size_t)i0 * 25 + (f0 - A_FL));
                *reinterpret_cast<f32x4*>(&sAB[f0]) = v;
            }
        }
    }
    bar_lgkm();

    const bool g1v = (tid + 320) < 544;  // second stage slot valid for tid<224
    for (; tile < NTILES; tile += GRID) {
        const int  next      = tile + GRID;
        const bool have_next = next < NTILES;

        // ---- issue next tile's loads into registers ----
        f32x4 g0, g1;
        if (have_next) {
            const int i0 = next * 64;
            const int f0 = tid * 4;                  // 0..1276
            g0 = (f0 < A_FL)
                ? *reinterpret_cast<const f32x4*>(A + (size_t)i0 * 9 + f0)
                : *reinterpret_cast<const f32x4*>(B + (size_t)i0 * 25 + (f0 - A_FL));
            if (g1v) {
                const int f1 = (tid + 320) * 4;      // 1280..2172, always B side
                g1 = *reinterpret_cast<const f32x4*>(B + (size_t)i0 * 25 + (f1 - A_FL));
            }
        }

        // ---- compute from sAB ----
        float av[9];
        #pragma unroll
        for (int k = 0; k < 9; ++k) av[k] = sAB[i_loc * 9 + k];
        float bv[25];
        #pragma unroll
        for (int k = 0; k < 25; ++k) bv[k] = sAB[A_FL + i_loc * 25 + k];

        // T[m][b] = sum_n bv[n][b] * cr[m][n]
        float T[3][5];
        #pragma unroll
        for (int m = 0; m < 3; ++m) {
            #pragma unroll
            for (int b = 0; b < 5; ++b) {
                float t = 0.0f;
                #pragma unroll
                for (int n = 0; n < 5; ++n)
                    t = fmaf(bv[n * 5 + b], cr[m][n], t);
                T[m][b] = t;
            }
        }
        // out[a][b] = sum_m av[m][a] * T[m][b]
        #pragma unroll
        for (int a = 0; a < 3; ++a) {
            #pragma unroll
            for (int b = 0; b < 5; ++b) {
                float acc = 0.0f;
                #pragma unroll
                for (int m = 0; m < 3; ++m)
                    acc = fmaf(av[m * 3 + a], T[m][b], acc);
                sO[tid * 15 + a * 5 + b] = acc;
            }
        }

        bar_lgkm();   // all sAB reads + sO writes complete; NO store drain

        // ---- flush sO -> global, nontemporal coalesced float4 ----
        float* obase = out + (size_t)tile * O_FL;
        #pragma unroll
        for (int jj = 0; jj < 4; ++jj) {
            int j = tid + jj * 320;
            if (j < 1200) {
                f32x4 v = *reinterpret_cast<const f32x4*>(&sO[4 * j]);
                __builtin_nontemporal_store(v, reinterpret_cast<f32x4*>(obase + 4 * j));
            }
        }

        // keep flush stores ordered before the g-dependent ds_writes so the
        // implicit wait is a counted vmcnt(4), not a store drain
        asm volatile("" ::: "memory");

        // ---- stage-write regs -> sAB (same buffer; reads all done) ----
        if (have_next) {
            *reinterpret_cast<f32x4*>(&sAB[tid * 4]) = g0;
            if (g1v)
                *reinterpret_cast<f32x4*>(&sAB[(tid + 320) * 4]) = g1;
        }

        bar_lgkm();
    }
}

extern "C" void kernel_launch(void* const* d_in, const int* in_sizes, int n_in,
                              void* d_out, int out_size, void* d_ws, size_t ws_size,
                              hipStream_t stream) {
    const float* A = (const float*)d_in[0];
    const float* B = (const float*)d_in[1];
    const float* C = (const float*)d_in[2];
    float* out = (float*)d_out;

    tb_kernel<<<GRID, 320, 0, stream>>>(A, B, C, out);
}